// Round 17
// baseline (493.699 us; speedup 1.0000x reference)
//
#include <hip/hip_runtime.h>
#include <math.h>

// Round 17: interleaved block roles in the hybrid kernels (r16 front-loaded all
// hist blocks first -> phases serialized; now hist/gemm alternate via blockIdx&1
// so both are co-resident the whole kernel). Same for scatter/alpha. All compute
// bodies byte-identical to round 16.

#define NEG_SLOPE 0.2f

typedef __attribute__((ext_vector_type(8))) short bf16x8;
typedef __attribute__((ext_vector_type(4))) float f32x4;
typedef __attribute__((ext_vector_type(2))) float f32x2;

__device__ __forceinline__ unsigned short f2bf(float f) {
  unsigned int u = __float_as_uint(f);
  u = (u + 0x7FFFu + ((u >> 16) & 1u)) >> 16;  // RNE
  return (unsigned short)u;
}
__device__ __forceinline__ float bf2f(unsigned short u) {
  return __uint_as_float((unsigned int)u << 16);
}
__device__ __forceinline__ f32x2 unpk(unsigned int u) {
  f32x2 r;
  r.x = __uint_as_float(u << 16);
  r.y = __uint_as_float(u & 0xFFFF0000u);
  return r;
}
__device__ __forceinline__ int rl_i(int v, int l) {
  return __builtin_amdgcn_readlane(v, l);
}
__device__ __forceinline__ float rl_f(float v, int l) {
  return __uint_as_float(__builtin_amdgcn_readlane(__float_as_uint(v), l));
}
// interleave helper: maps bid -> (isA, idx) with A/B alternating while both remain
__device__ __forceinline__ void role2(int bid, int nA, int nB, bool& isA, int& idx) {
  const int nmin = nA < nB ? nA : nB;
  if (bid < 2 * nmin) {
    isA = (bid & 1) == 0;
    idx = bid >> 1;
  } else {
    isA = nA > nB;
    idx = nmin + (bid - 2 * nmin);
  }
}

#define GLOAD16(g, l)                                                   \
  __builtin_amdgcn_global_load_lds(                                     \
      (const __attribute__((address_space(1))) void*)(g),               \
      (__attribute__((address_space(3))) void*)(l), 16, 0, 0)

// ---------------- weight conversions ----------------
__global__ __launch_bounds__(256) void wt_bf16_all(const float* __restrict__ W_sp,
                                                   const float* __restrict__ W_gs,
                                                   const float* __restrict__ W_fu,
                                                   unsigned short* __restrict__ wt_sp,
                                                   unsigned short* __restrict__ wt_gs,
                                                   unsigned short* __restrict__ wt_fu) {
  const int i = blockIdx.x * 256 + threadIdx.x;
  if (i < 131072) {
    const int k = i >> 8, n = i & 255;
    wt_sp[n * 512 + k] = f2bf(W_sp[i]);
  } else if (i < 262144) {
    const int j = i - 131072;
    const int k = j >> 8, n = j & 255;
    wt_gs[n * 512 + k] = f2bf(W_gs[j]);
  } else if (i < 278528) {
    const int j = i - 262144;
    const int k = j >> 6, n = j & 63;
    wt_fu[n * 256 + k] = f2bf(W_fu[j]);
  }
}

// ---------------- scans ----------------
__global__ __launch_bounds__(256) void scan1_2(const int* __restrict__ deg_sp,
                                               const int* __restrict__ deg_gs,
                                               int* __restrict__ rs_sp,
                                               int* __restrict__ rs_gs,
                                               int* __restrict__ parts2, int N) {
  __shared__ int sm[256];
  const int* deg = blockIdx.y ? deg_gs : deg_sp;
  int* rs = blockIdx.y ? rs_gs : rs_sp;
  int* parts = parts2 + blockIdx.y * 512;
  const int i = blockIdx.x * 256 + threadIdx.x;
  const int v = (i < N) ? deg[i] : 0;
  sm[threadIdx.x] = v;
  __syncthreads();
  for (int off = 1; off < 256; off <<= 1) {
    const int x = (threadIdx.x >= off) ? sm[threadIdx.x - off] : 0;
    __syncthreads();
    sm[threadIdx.x] += x;
    __syncthreads();
  }
  if (i < N) rs[i] = sm[threadIdx.x] - v;
  if (threadIdx.x == 255) parts[blockIdx.x] = sm[255];
}

__global__ __launch_bounds__(512) void scan2_2(int* __restrict__ parts2, int nb) {
  __shared__ int sm[512];
  int* parts = parts2 + blockIdx.x * 512;
  const int t = threadIdx.x;
  const int v = (t < nb) ? parts[t] : 0;
  sm[t] = v;
  __syncthreads();
  for (int off = 1; off < 512; off <<= 1) {
    const int x = (t >= off) ? sm[t - off] : 0;
    __syncthreads();
    sm[t] += x;
    __syncthreads();
  }
  if (t < nb) parts[t] = sm[t] - v;
}

__global__ __launch_bounds__(256) void scan3_2(int* __restrict__ rs_sp,
                                               int* __restrict__ rs_gs,
                                               const int* __restrict__ parts2,
                                               int N, int E) {
  int* rs = blockIdx.y ? rs_gs : rs_sp;
  const int* parts = parts2 + blockIdx.y * 512;
  const int i = blockIdx.x * 256 + threadIdx.x;
  if (i < N) rs[i] += parts[blockIdx.x];
  if (i == 0) rs[N] = E;
}

// ---------------- hybrid: edge histogram + layer-1 GEMM (interleaved roles) --------
__global__ __launch_bounds__(512) void gemm2_hist(const float* __restrict__ x,
                                                  const unsigned short* __restrict__ wsp,
                                                  const unsigned short* __restrict__ wgs,
                                                  unsigned short* __restrict__ hb_sp,
                                                  unsigned short* __restrict__ hb_gs,
                                                  const int* __restrict__ dst_sp,
                                                  const int* __restrict__ dst_gs,
                                                  int* __restrict__ deg_sp,
                                                  int* __restrict__ deg_gs,
                                                  int* __restrict__ ord_sp,
                                                  int* __restrict__ ord_gs,
                                                  int nHist, int nGemm, int E, int M) {
  bool isHist;
  int idx;
  role2(blockIdx.x, nHist, nGemm, isHist, idx);
  if (isHist) {
    const int m = idx * 512 + threadIdx.x;
    if (m < E) {
      ord_sp[m] = atomicAdd(&deg_sp[dst_sp[m]], 1);
      ord_gs[m] = atomicAdd(&deg_gs[dst_gs[m]], 1);
    }
    return;
  }
  // ---- gemm2 body (round-7 exact) ----
  __shared__ unsigned short sA[64 * 64];
  __shared__ unsigned short sW[2][256 * 64];
  const int tid = threadIdx.x;
  const int w = tid >> 6, l = tid & 63;
  const int whalf = w >> 2;
  const int wq = w & 3;
  const int bm = idx * 64;

  const int arow0 = tid >> 4;
  const int acol4 = (tid & 15) * 4;
  const unsigned short* __restrict__ wtp = whalf ? wgs : wsp;
  const int wrow_in_ch = l >> 3;
  const int wbyte = ((l & 7) * 16) ^ ((wrow_in_ch & 7) << 4);

  f32x4 acc[4][4] = {};
  for (int k0 = 0; k0 < 512; k0 += 64) {
    __syncthreads();
#pragma unroll
    for (int r = 0; r < 2; ++r) {
      const int row = arow0 + r * 32;
      int grow = bm + row;
      grow = grow < M ? grow : M - 1;
      const float4 v = *(const float4*)(x + (size_t)grow * 512 + k0 + acol4);
      ushort4 o;
      o.x = f2bf(v.x); o.y = f2bf(v.y); o.z = f2bf(v.z); o.w = f2bf(v.w);
      const int byte = (row * 128 + acol4 * 2) ^ ((row & 7) << 4);
      *(ushort4*)(((char*)sA) + byte) = o;
    }
#pragma unroll
    for (int c = 0; c < 8; ++c) {
      const int ch = c * 4 + wq;
      const int grow = ch * 8 + wrow_in_ch;
      const char* g = (const char*)wtp + (size_t)grow * 1024 + (size_t)k0 * 2 + wbyte;
      GLOAD16(g, ((char*)sW[whalf]) + ch * 1024);
    }
    __syncthreads();
#pragma unroll
    for (int ks = 0; ks < 2; ++ks) {
      const int cb = ks * 64 + (l >> 4) * 16;
      bf16x8 af[4], bf[4];
#pragma unroll
      for (int m = 0; m < 4; ++m) {
        const int r = m * 16 + (l & 15);
        af[m] = *(const bf16x8*)(((const char*)sA) + r * 128 + (cb ^ ((r & 7) << 4)));
      }
#pragma unroll
      for (int n = 0; n < 4; ++n) {
        const int r = wq * 64 + n * 16 + (l & 15);
        bf[n] = *(const bf16x8*)(((const char*)sW[whalf]) + r * 128 + (cb ^ ((r & 7) << 4)));
      }
#pragma unroll
      for (int m = 0; m < 4; ++m)
#pragma unroll
        for (int n = 0; n < 4; ++n)
          acc[m][n] = __builtin_amdgcn_mfma_f32_16x16x32_bf16(af[m], bf[n], acc[m][n], 0, 0, 0);
    }
  }
  unsigned short* __restrict__ outp = whalf ? hb_gs : hb_sp;
#pragma unroll
  for (int m = 0; m < 4; ++m) {
#pragma unroll
    for (int r = 0; r < 4; ++r) {
      const int row = bm + m * 16 + (l >> 4) * 4 + r;
      if (row < M) {
#pragma unroll
        for (int n = 0; n < 4; ++n)
          outp[(size_t)row * 256 + wq * 64 + n * 16 + (l & 15)] = f2bf(acc[m][n][r]);
      }
    }
  }
}

// ---------------- hybrid: CSR scatter + dual alpha (interleaved roles) -------------
__global__ __launch_bounds__(256) void alpha_scatter(const ushort4* __restrict__ hsp,
                                                     const ushort4* __restrict__ hgs,
                                                     const float* __restrict__ av_sp_s,
                                                     const float* __restrict__ av_sp_d,
                                                     const float* __restrict__ av_gs_s,
                                                     const float* __restrict__ av_gs_d,
                                                     float* __restrict__ asrc_sp,
                                                     float* __restrict__ adst_sp,
                                                     float* __restrict__ asrc_gs,
                                                     float* __restrict__ adst_gs,
                                                     const int* __restrict__ ei_sp,
                                                     const int* __restrict__ ei_gs,
                                                     const int* __restrict__ rs_sp,
                                                     const int* __restrict__ rs_gs,
                                                     const int* __restrict__ ord_sp,
                                                     const int* __restrict__ ord_gs,
                                                     int* __restrict__ csr_sp,
                                                     int* __restrict__ csr_gs,
                                                     int nScat, int nAlpha, int E, int N) {
  bool isScat;
  int idx;
  role2(blockIdx.x, nScat, nAlpha, isScat, idx);
  if (isScat) {
    const int m = idx * 256 + threadIdx.x;
    if (m < E) {
      csr_sp[rs_sp[ei_sp[E + m]] + ord_sp[m]] = ei_sp[m];
      csr_gs[rs_gs[ei_gs[E + m]] + ord_gs[m]] = ei_gs[m];
    }
    return;
  }
  const int wave = (int)(((size_t)idx * 256 + threadIdx.x) >> 6);
  const int lane = threadIdx.x & 63;
  if (wave >= N) return;
  const ushort4 h1 = hsp[(size_t)wave * 64 + lane];
  const ushort4 h2 = hgs[(size_t)wave * 64 + lane];
  const float4 s1 = ((const float4*)av_sp_s)[lane];
  const float4 d1 = ((const float4*)av_sp_d)[lane];
  const float4 s2 = ((const float4*)av_gs_s)[lane];
  const float4 d2 = ((const float4*)av_gs_d)[lane];
  const float a0 = bf2f(h1.x), a1 = bf2f(h1.y), a2 = bf2f(h1.z), a3 = bf2f(h1.w);
  const float b0 = bf2f(h2.x), b1 = bf2f(h2.y), b2 = bf2f(h2.z), b3 = bf2f(h2.w);
  float p0 = a0 * s1.x + a1 * s1.y + a2 * s1.z + a3 * s1.w;
  float p1 = a0 * d1.x + a1 * d1.y + a2 * d1.z + a3 * d1.w;
  float p2 = b0 * s2.x + b1 * s2.y + b2 * s2.z + b3 * s2.w;
  float p3 = b0 * d2.x + b1 * d2.y + b2 * d2.z + b3 * d2.w;
#pragma unroll
  for (int off = 32; off; off >>= 1) {
    p0 += __shfl_down(p0, off);
    p1 += __shfl_down(p1, off);
    p2 += __shfl_down(p2, off);
    p3 += __shfl_down(p3, off);
  }
  if (lane == 0) {
    asrc_sp[wave] = p0; adst_sp[wave] = p1;
    asrc_gs[wave] = p2; adst_gs[wave] = p3;
  }
}

// ---------------- fusion GEMM (256->64) + in-wave alpha epilogue ----------------
__global__ __launch_bounds__(256) void gemm_fu_alpha(const unsigned short* __restrict__ A,
                                                     const unsigned short* __restrict__ Bt,
                                                     const float* __restrict__ avs,
                                                     const float* __restrict__ avd,
                                                     unsigned short* __restrict__ C,
                                                     float* __restrict__ asrc,
                                                     float* __restrict__ adst,
                                                     int M) {
  constexpr int K = 256, Nc = 64;
  __shared__ unsigned short sA[128 * 64];
  __shared__ unsigned short sB[64 * 64];
  const int tid = threadIdx.x;
  const int w = tid >> 6, l = tid & 63;
  const int bm = blockIdx.x * 128;
  const int crow = l >> 3;
  const int cbyte = (l & 7) * 16;

  f32x4 acc[2][4] = {};
  for (int k0 = 0; k0 < K; k0 += 64) {
    __syncthreads();
#pragma unroll
    for (int c = 0; c < 4; ++c) {
      const int ch = w * 4 + c;
      int row = bm + ch * 8 + crow;
      row = row < M ? row : M - 1;
      const char* g = (const char*)A + (size_t)row * K * 2 + (size_t)k0 * 2 + cbyte;
      GLOAD16(g, ((char*)sA) + ch * 1024);
    }
#pragma unroll
    for (int c = 0; c < 2; ++c) {
      const int ch = w * 2 + c;
      const int row = ch * 8 + crow;
      const char* g = (const char*)Bt + (size_t)row * K * 2 + (size_t)k0 * 2 + cbyte;
      GLOAD16(g, ((char*)sB) + ch * 1024);
    }
    __syncthreads();
#pragma unroll
    for (int ks = 0; ks < 2; ++ks) {
      bf16x8 af[2], bfr[4];
#pragma unroll
      for (int m = 0; m < 2; ++m) {
        const int r = w * 32 + m * 16 + (l & 15);
        af[m] = *(const bf16x8*)&sA[r * 64 + ks * 32 + (l >> 4) * 8];
      }
#pragma unroll
      for (int n = 0; n < 4; ++n) {
        const int r = n * 16 + (l & 15);
        bfr[n] = *(const bf16x8*)&sB[r * 64 + ks * 32 + (l >> 4) * 8];
      }
#pragma unroll
      for (int m = 0; m < 2; ++m)
#pragma unroll
        for (int n = 0; n < 4; ++n)
          acc[m][n] = __builtin_amdgcn_mfma_f32_16x16x32_bf16(af[m], bfr[n], acc[m][n], 0, 0, 0);
    }
  }
  float as_v[4], ad_v[4];
#pragma unroll
  for (int n = 0; n < 4; ++n) {
    as_v[n] = avs[n * 16 + (l & 15)];
    ad_v[n] = avd[n * 16 + (l & 15)];
  }
#pragma unroll
  for (int m = 0; m < 2; ++m) {
#pragma unroll
    for (int r = 0; r < 4; ++r) {
      const int row = bm + w * 32 + m * 16 + (l >> 4) * 4 + r;
      if (row < M) {
#pragma unroll
        for (int n = 0; n < 4; ++n)
          C[(size_t)row * Nc + n * 16 + (l & 15)] = f2bf(acc[m][n][r]);
      }
      float ps = acc[m][0][r] * as_v[0] + acc[m][1][r] * as_v[1] +
                 acc[m][2][r] * as_v[2] + acc[m][3][r] * as_v[3];
      float pd = acc[m][0][r] * ad_v[0] + acc[m][1][r] * ad_v[1] +
                 acc[m][2][r] * ad_v[2] + acc[m][3][r] * ad_v[3];
#pragma unroll
      for (int off = 1; off < 16; off <<= 1) {
        ps += __shfl_xor(ps, off);
        pd += __shfl_xor(pd, off);
      }
      if ((l & 15) == 0 && row < M) {
        asrc[row] = ps;
        adst[row] = pd;
      }
    }
  }
}

// ---------------- merged dual-graph aggregation + blend, H=256 ----------------
__global__ __launch_bounds__(256) void agg2_blend(const int* __restrict__ rs_sp,
                                                  const int* __restrict__ csr_sp,
                                                  const int* __restrict__ rs_gs,
                                                  const int* __restrict__ csr_gs,
                                                  const float* __restrict__ asrc_sp,
                                                  const float* __restrict__ adst_sp,
                                                  const float* __restrict__ asrc_gs,
                                                  const float* __restrict__ adst_gs,
                                                  const uint2* __restrict__ hsp4,
                                                  const uint2* __restrict__ hgs4,
                                                  const float* __restrict__ b_sp,
                                                  const float* __restrict__ b_gs,
                                                  ushort4* __restrict__ out16, int N) {
  const int d = (int)((blockIdx.x * (size_t)blockDim.x + threadIdx.x) >> 6);
  const int lane = threadIdx.x & 63;
  if (d >= N) return;

  float v_sp[4], v_gs[4];
#pragma unroll
  for (int g = 0; g < 2; ++g) {
    const int* __restrict__ rs   = g ? rs_gs : rs_sp;
    const int* __restrict__ csr  = g ? csr_gs : csr_sp;
    const float* __restrict__ as = g ? asrc_gs : asrc_sp;
    const float* __restrict__ adp = g ? adst_gs : adst_sp;
    const uint2* __restrict__ h4 = g ? hgs4 : hsp4;
    const float* __restrict__ bias = g ? b_gs : b_sp;
    float* __restrict__ vout = g ? v_gs : v_sp;

    const float ad = adp[d];
    float e = as[d] + ad;
    e = e > 0.f ? e : NEG_SLOPE * e;
    const float wself = expf(e);
    float denl = (lane == 0) ? wself : 0.f;
    const uint2 hv = h4[(size_t)d * 64 + lane];
    f32x2 axy = unpk(hv.x) * wself;
    f32x2 azw = unpk(hv.y) * wself;

    const int base = rs[d], mend = rs[d + 1];
    for (int c = base; c < mend; c += 64) {
      const int m = c + lane;
      int s = 0;
      float w = 0.f;
      if (m < mend) {
        s = csr[m];
        float e2 = as[s] + ad;
        e2 = e2 > 0.f ? e2 : NEG_SLOPE * e2;
        w = expf(e2);
      }
      denl += w;
      const int cnt = min(64, mend - c);
      int j = 0;
      for (; j + 3 < cnt; j += 4) {
        const int s0 = rl_i(s, j), s1 = rl_i(s, j + 1), s2 = rl_i(s, j + 2), s3 = rl_i(s, j + 3);
        const float w0 = rl_f(w, j), w1 = rl_f(w, j + 1), w2 = rl_f(w, j + 2), w3 = rl_f(w, j + 3);
        const uint2 a0 = h4[(size_t)s0 * 64 + lane];
        const uint2 a1 = h4[(size_t)s1 * 64 + lane];
        const uint2 a2 = h4[(size_t)s2 * 64 + lane];
        const uint2 a3 = h4[(size_t)s3 * 64 + lane];
        axy += unpk(a0.x) * w0;  azw += unpk(a0.y) * w0;
        axy += unpk(a1.x) * w1;  azw += unpk(a1.y) * w1;
        axy += unpk(a2.x) * w2;  azw += unpk(a2.y) * w2;
        axy += unpk(a3.x) * w3;  azw += unpk(a3.y) * w3;
      }
      for (; j < cnt; ++j) {
        const int sj = rl_i(s, j);
        const float wj = rl_f(w, j);
        const uint2 aj = h4[(size_t)sj * 64 + lane];
        axy += unpk(aj.x) * wj;
        azw += unpk(aj.y) * wj;
      }
    }
#pragma unroll
    for (int off = 32; off; off >>= 1) denl += __shfl_xor(denl, off);
    const float inv = 1.f / denl;
    const float4 b4 = ((const float4*)bias)[lane];
    vout[0] = axy.x * inv + b4.x;
    vout[1] = axy.y * inv + b4.y;
    vout[2] = azw.x * inv + b4.z;
    vout[3] = azw.y * inv + b4.w;
#pragma unroll
    for (int j2 = 0; j2 < 4; ++j2)
      vout[j2] = vout[j2] > 0.f ? vout[j2] : (expf(vout[j2]) - 1.f);
  }

  ushort4 pk;
  pk.x = f2bf(0.5f * v_gs[0] + 0.5f * v_sp[0]);
  pk.y = f2bf(0.5f * v_gs[1] + 0.5f * v_sp[1]);
  pk.z = f2bf(0.5f * v_gs[2] + 0.5f * v_sp[2]);
  pk.w = f2bf(0.5f * v_gs[3] + 0.5f * v_sp[3]);
  out16[(size_t)d * 64 + lane] = pk;
}

// ---------------- fused CSR aggregation, H=64, bf16 h -> fp32 d_out ----------------
__global__ __launch_bounds__(256) void agg_csr64(const int* __restrict__ rs,
                                                 const int* __restrict__ csr,
                                                 const float* __restrict__ asrc,
                                                 const float* __restrict__ adst,
                                                 const unsigned short* __restrict__ h,
                                                 const float* __restrict__ bias,
                                                 float* __restrict__ outb, int N) {
  const int d = (int)((blockIdx.x * (size_t)blockDim.x + threadIdx.x) >> 6);
  const int lane = threadIdx.x & 63;
  if (d >= N) return;
  const float ad = adst[d];

  float e = asrc[d] + ad;
  e = e > 0.f ? e : NEG_SLOPE * e;
  const float wself = expf(e);
  float denl = (lane == 0) ? wself : 0.f;
  f32x2 acc2;
  acc2.x = wself * bf2f(h[(size_t)d * 64 + lane]);
  acc2.y = 0.f;

  const int base = rs[d], mend = rs[d + 1];
  for (int c = base; c < mend; c += 64) {
    const int m = c + lane;
    int s = 0;
    float w = 0.f;
    if (m < mend) {
      s = csr[m];
      float e2 = asrc[s] + ad;
      e2 = e2 > 0.f ? e2 : NEG_SLOPE * e2;
      w = expf(e2);
    }
    denl += w;
    const int cnt = min(64, mend - c);
    int j = 0;
    for (; j + 3 < cnt; j += 4) {
      const int s0 = rl_i(s, j), s1 = rl_i(s, j + 1), s2 = rl_i(s, j + 2), s3 = rl_i(s, j + 3);
      const float w0 = rl_f(w, j), w1 = rl_f(w, j + 1), w2 = rl_f(w, j + 2), w3 = rl_f(w, j + 3);
      f32x2 h01, h23, w01, w23;
      h01.x = bf2f(h[(size_t)s0 * 64 + lane]);
      h01.y = bf2f(h[(size_t)s1 * 64 + lane]);
      h23.x = bf2f(h[(size_t)s2 * 64 + lane]);
      h23.y = bf2f(h[(size_t)s3 * 64 + lane]);
      w01.x = w0; w01.y = w1;
      w23.x = w2; w23.y = w3;
      acc2 += h01 * w01;
      acc2 += h23 * w23;
    }
    for (; j < cnt; ++j) {
      const int sj = rl_i(s, j);
      const float wj = rl_f(w, j);
      acc2.x += wj * bf2f(h[(size_t)sj * 64 + lane]);
    }
  }
  float acc = acc2.x + acc2.y;
#pragma unroll
  for (int off = 32; off; off >>= 1) denl += __shfl_xor(denl, off);
  outb[(size_t)d * 64 + lane] = acc / denl + bias[lane];
}

extern "C" void kernel_launch(void* const* d_in, const int* in_sizes, int n_in,
                              void* d_out, int out_size, void* d_ws, size_t ws_size,
                              hipStream_t stream) {
  const float* x        = (const float*)d_in[0];
  const int*   ei_sp    = (const int*)d_in[1];
  const int*   ei_gs    = (const int*)d_in[2];
  const float* W_sp     = (const float*)d_in[3];
  const float* a_src_sp = (const float*)d_in[4];
  const float* a_dst_sp = (const float*)d_in[5];
  const float* b_sp     = (const float*)d_in[6];
  const float* W_gs     = (const float*)d_in[7];
  const float* a_src_gs = (const float*)d_in[8];
  const float* a_dst_gs = (const float*)d_in[9];
  const float* b_gs     = (const float*)d_in[10];
  const float* W_fu     = (const float*)d_in[11];
  const float* a_src_fu = (const float*)d_in[12];
  const float* a_dst_fu = (const float*)d_in[13];
  const float* b_fu     = (const float*)d_in[14];
  float* out = (float*)d_out;

  const int N = in_sizes[0] / 512;
  const int E = in_sizes[1] / 2;
  const int nb = (N + 255) / 256;

  // ---- workspace layout ----
  unsigned short* wt_sp = (unsigned short*)d_ws;       // 256*512
  unsigned short* wt_gs = wt_sp + 256 * 512;           // 256*512
  unsigned short* wt_fu = wt_gs + 256 * 512;           // 64*256
  unsigned short* hb_sp = wt_fu + 64 * 256;            // N*256 bf16
  unsigned short* hb_gs = hb_sp + (size_t)N * 256;     // N*256 bf16
  unsigned short* hfb   = hb_gs + (size_t)N * 256;     // N*256 bf16 h_fused
  unsigned short* hfu   = hfb + (size_t)N * 256;       // N*64 bf16
  float* asrc_sp = (float*)(hfu + (size_t)N * 64);     // N
  float* adst_sp = asrc_sp + N;                        // N
  float* asrc_gs = adst_sp + N;                        // N
  float* adst_gs = asrc_gs + N;                        // N
  int* rs_sp  = (int*)(adst_gs + N);                   // N+1
  int* rs_gs  = rs_sp + (N + 1);                       // N+1
  int* csr_sp = rs_gs + (N + 1);                       // E
  int* csr_gs = csr_sp + E;                            // E
  int* deg_sp = csr_gs + E;                            // N
  int* deg_gs = deg_sp + N;                            // N
  int* parts2 = deg_gs + N;                            // 2*512
  int* ord_sp = parts2 + 1024;                         // E
  int* ord_gs = ord_sp + E;                            // E

  const int BLK = 256;
  const int nodeWaveGrid = (N + 3) / 4;
  const int nHist = (E + 511) / 512;
  const int nGemm = (N + 63) / 64;
  const int nScat = (E + 255) / 256;

  // ---- weights first (gemm blocks read them) ----
  wt_bf16_all<<<(278528 + 255) / 256, BLK, 0, stream>>>(W_sp, W_gs, W_fu,
                                                        wt_sp, wt_gs, wt_fu);
  hipMemsetAsync(deg_sp, 0, (size_t)2 * N * 4, stream);

  // ---- hybrid 1: edge histogram + layer-1 GEMMs (interleaved roles) ----
  gemm2_hist<<<nHist + nGemm, 512, 0, stream>>>(x, wt_sp, wt_gs, hb_sp, hb_gs,
                                                ei_sp + E, ei_gs + E,
                                                deg_sp, deg_gs, ord_sp, ord_gs,
                                                nHist, nGemm, E, N);

  // ---- scans ----
  scan1_2<<<dim3(nb, 2), BLK, 0, stream>>>(deg_sp, deg_gs, rs_sp, rs_gs, parts2, N);
  scan2_2<<<2, 512, 0, stream>>>(parts2, nb);
  scan3_2<<<dim3(nb, 2), BLK, 0, stream>>>(rs_sp, rs_gs, parts2, N, E);

  // ---- hybrid 2: CSR scatter + dual alpha (interleaved roles) ----
  alpha_scatter<<<nScat + nodeWaveGrid, BLK, 0, stream>>>(
      (const ushort4*)hb_sp, (const ushort4*)hb_gs,
      a_src_sp, a_dst_sp, a_src_gs, a_dst_gs,
      asrc_sp, adst_sp, asrc_gs, adst_gs,
      ei_sp, ei_gs, rs_sp, rs_gs, ord_sp, ord_gs,
      csr_sp, csr_gs, nScat, nodeWaveGrid, E, N);

  // ---- merged dual-graph aggregation + blend -> h_fused bf16 ----
  agg2_blend<<<nodeWaveGrid, BLK, 0, stream>>>(rs_sp, csr_sp, rs_gs, csr_gs,
                                               asrc_sp, adst_sp, asrc_gs, adst_gs,
                                               (const uint2*)hb_sp,
                                               (const uint2*)hb_gs,
                                               b_sp, b_gs, (ushort4*)hfb, N);

  // ---- fusion conv (256->64, spatial graph) + in-wave alpha epilogue ----
  gemm_fu_alpha<<<(N + 127) / 128, BLK, 0, stream>>>(hfb, wt_fu, a_src_fu, a_dst_fu,
                                                     hfu, asrc_sp, adst_sp, N);
  agg_csr64<<<nodeWaveGrid, BLK, 0, stream>>>(rs_sp, csr_sp, asrc_sp, adst_sp,
                                              hfu, b_fu, out, N);
}

// Round 18
// 451.079 us; speedup vs baseline: 1.0945x; 1.0945x over previous
//
#include <hip/hip_runtime.h>
#include <math.h>

// Round 18: revert to the round-16 exact configuration (best: 452.5us).
// Round-17's interleaved block roles regressed (-41us): co-resident hist blocks
// carry the kernel's static 72KB LDS allocation without using it, capping gemm
// occupancy (39->26.6%), and their random atomics compete with weight streams in
// L2. Front-loaded hist (r16) lets those blocks burst through and vacate.
//  - gemm2_hist: blocks [0,nHist) = edge histogram, rest = r7-exact gemm2 body.
//  - alpha_scatter: blocks [0,nScat) = atomic-free CSR scatter, rest = dual alpha.
//  - agg2_blend: merged dual-graph gather + ELU + blend (packed f32).
//  - gemm_fu_alpha: fusion GEMM with in-wave alpha epilogue.

#define NEG_SLOPE 0.2f

typedef __attribute__((ext_vector_type(8))) short bf16x8;
typedef __attribute__((ext_vector_type(4))) float f32x4;
typedef __attribute__((ext_vector_type(2))) float f32x2;

__device__ __forceinline__ unsigned short f2bf(float f) {
  unsigned int u = __float_as_uint(f);
  u = (u + 0x7FFFu + ((u >> 16) & 1u)) >> 16;  // RNE
  return (unsigned short)u;
}
__device__ __forceinline__ float bf2f(unsigned short u) {
  return __uint_as_float((unsigned int)u << 16);
}
__device__ __forceinline__ f32x2 unpk(unsigned int u) {
  f32x2 r;
  r.x = __uint_as_float(u << 16);
  r.y = __uint_as_float(u & 0xFFFF0000u);
  return r;
}
__device__ __forceinline__ int rl_i(int v, int l) {
  return __builtin_amdgcn_readlane(v, l);
}
__device__ __forceinline__ float rl_f(float v, int l) {
  return __uint_as_float(__builtin_amdgcn_readlane(__float_as_uint(v), l));
}

#define GLOAD16(g, l)                                                   \
  __builtin_amdgcn_global_load_lds(                                     \
      (const __attribute__((address_space(1))) void*)(g),               \
      (__attribute__((address_space(3))) void*)(l), 16, 0, 0)

// ---------------- weight conversions ----------------
__global__ __launch_bounds__(256) void wt_bf16_all(const float* __restrict__ W_sp,
                                                   const float* __restrict__ W_gs,
                                                   const float* __restrict__ W_fu,
                                                   unsigned short* __restrict__ wt_sp,
                                                   unsigned short* __restrict__ wt_gs,
                                                   unsigned short* __restrict__ wt_fu) {
  const int i = blockIdx.x * 256 + threadIdx.x;
  if (i < 131072) {
    const int k = i >> 8, n = i & 255;
    wt_sp[n * 512 + k] = f2bf(W_sp[i]);
  } else if (i < 262144) {
    const int j = i - 131072;
    const int k = j >> 8, n = j & 255;
    wt_gs[n * 512 + k] = f2bf(W_gs[j]);
  } else if (i < 278528) {
    const int j = i - 262144;
    const int k = j >> 6, n = j & 63;
    wt_fu[n * 256 + k] = f2bf(W_fu[j]);
  }
}

// ---------------- scans ----------------
__global__ __launch_bounds__(256) void scan1_2(const int* __restrict__ deg_sp,
                                               const int* __restrict__ deg_gs,
                                               int* __restrict__ rs_sp,
                                               int* __restrict__ rs_gs,
                                               int* __restrict__ parts2, int N) {
  __shared__ int sm[256];
  const int* deg = blockIdx.y ? deg_gs : deg_sp;
  int* rs = blockIdx.y ? rs_gs : rs_sp;
  int* parts = parts2 + blockIdx.y * 512;
  const int i = blockIdx.x * 256 + threadIdx.x;
  const int v = (i < N) ? deg[i] : 0;
  sm[threadIdx.x] = v;
  __syncthreads();
  for (int off = 1; off < 256; off <<= 1) {
    const int x = (threadIdx.x >= off) ? sm[threadIdx.x - off] : 0;
    __syncthreads();
    sm[threadIdx.x] += x;
    __syncthreads();
  }
  if (i < N) rs[i] = sm[threadIdx.x] - v;
  if (threadIdx.x == 255) parts[blockIdx.x] = sm[255];
}

__global__ __launch_bounds__(512) void scan2_2(int* __restrict__ parts2, int nb) {
  __shared__ int sm[512];
  int* parts = parts2 + blockIdx.x * 512;
  const int t = threadIdx.x;
  const int v = (t < nb) ? parts[t] : 0;
  sm[t] = v;
  __syncthreads();
  for (int off = 1; off < 512; off <<= 1) {
    const int x = (t >= off) ? sm[t - off] : 0;
    __syncthreads();
    sm[t] += x;
    __syncthreads();
  }
  if (t < nb) parts[t] = sm[t] - v;
}

__global__ __launch_bounds__(256) void scan3_2(int* __restrict__ rs_sp,
                                               int* __restrict__ rs_gs,
                                               const int* __restrict__ parts2,
                                               int N, int E) {
  int* rs = blockIdx.y ? rs_gs : rs_sp;
  const int* parts = parts2 + blockIdx.y * 512;
  const int i = blockIdx.x * 256 + threadIdx.x;
  if (i < N) rs[i] += parts[blockIdx.x];
  if (i == 0) rs[N] = E;
}

// ---------------- hybrid: edge histogram (blocks < nHist) + layer-1 GEMM -----------
__global__ __launch_bounds__(512) void gemm2_hist(const float* __restrict__ x,
                                                  const unsigned short* __restrict__ wsp,
                                                  const unsigned short* __restrict__ wgs,
                                                  unsigned short* __restrict__ hb_sp,
                                                  unsigned short* __restrict__ hb_gs,
                                                  const int* __restrict__ dst_sp,
                                                  const int* __restrict__ dst_gs,
                                                  int* __restrict__ deg_sp,
                                                  int* __restrict__ deg_gs,
                                                  int* __restrict__ ord_sp,
                                                  int* __restrict__ ord_gs,
                                                  int nHist, int E, int M) {
  if ((int)blockIdx.x < nHist) {
    const int m = blockIdx.x * 512 + threadIdx.x;
    if (m < E) {
      ord_sp[m] = atomicAdd(&deg_sp[dst_sp[m]], 1);
      ord_gs[m] = atomicAdd(&deg_gs[dst_gs[m]], 1);
    }
    return;
  }
  // ---- gemm2 body (round-7 exact) ----
  __shared__ unsigned short sA[64 * 64];
  __shared__ unsigned short sW[2][256 * 64];
  const int tid = threadIdx.x;
  const int w = tid >> 6, l = tid & 63;
  const int whalf = w >> 2;
  const int wq = w & 3;
  const int bm = (blockIdx.x - nHist) * 64;

  const int arow0 = tid >> 4;
  const int acol4 = (tid & 15) * 4;
  const unsigned short* __restrict__ wtp = whalf ? wgs : wsp;
  const int wrow_in_ch = l >> 3;
  const int wbyte = ((l & 7) * 16) ^ ((wrow_in_ch & 7) << 4);

  f32x4 acc[4][4] = {};
  for (int k0 = 0; k0 < 512; k0 += 64) {
    __syncthreads();
#pragma unroll
    for (int r = 0; r < 2; ++r) {
      const int row = arow0 + r * 32;
      int grow = bm + row;
      grow = grow < M ? grow : M - 1;
      const float4 v = *(const float4*)(x + (size_t)grow * 512 + k0 + acol4);
      ushort4 o;
      o.x = f2bf(v.x); o.y = f2bf(v.y); o.z = f2bf(v.z); o.w = f2bf(v.w);
      const int byte = (row * 128 + acol4 * 2) ^ ((row & 7) << 4);
      *(ushort4*)(((char*)sA) + byte) = o;
    }
#pragma unroll
    for (int c = 0; c < 8; ++c) {
      const int ch = c * 4 + wq;
      const int grow = ch * 8 + wrow_in_ch;
      const char* g = (const char*)wtp + (size_t)grow * 1024 + (size_t)k0 * 2 + wbyte;
      GLOAD16(g, ((char*)sW[whalf]) + ch * 1024);
    }
    __syncthreads();
#pragma unroll
    for (int ks = 0; ks < 2; ++ks) {
      const int cb = ks * 64 + (l >> 4) * 16;
      bf16x8 af[4], bf[4];
#pragma unroll
      for (int m = 0; m < 4; ++m) {
        const int r = m * 16 + (l & 15);
        af[m] = *(const bf16x8*)(((const char*)sA) + r * 128 + (cb ^ ((r & 7) << 4)));
      }
#pragma unroll
      for (int n = 0; n < 4; ++n) {
        const int r = wq * 64 + n * 16 + (l & 15);
        bf[n] = *(const bf16x8*)(((const char*)sW[whalf]) + r * 128 + (cb ^ ((r & 7) << 4)));
      }
#pragma unroll
      for (int m = 0; m < 4; ++m)
#pragma unroll
        for (int n = 0; n < 4; ++n)
          acc[m][n] = __builtin_amdgcn_mfma_f32_16x16x32_bf16(af[m], bf[n], acc[m][n], 0, 0, 0);
    }
  }
  unsigned short* __restrict__ outp = whalf ? hb_gs : hb_sp;
#pragma unroll
  for (int m = 0; m < 4; ++m) {
#pragma unroll
    for (int r = 0; r < 4; ++r) {
      const int row = bm + m * 16 + (l >> 4) * 4 + r;
      if (row < M) {
#pragma unroll
        for (int n = 0; n < 4; ++n)
          outp[(size_t)row * 256 + wq * 64 + n * 16 + (l & 15)] = f2bf(acc[m][n][r]);
      }
    }
  }
}

// ---------------- hybrid: CSR scatter (blocks < nScat) + dual alpha ----------------
__global__ __launch_bounds__(256) void alpha_scatter(const ushort4* __restrict__ hsp,
                                                     const ushort4* __restrict__ hgs,
                                                     const float* __restrict__ av_sp_s,
                                                     const float* __restrict__ av_sp_d,
                                                     const float* __restrict__ av_gs_s,
                                                     const float* __restrict__ av_gs_d,
                                                     float* __restrict__ asrc_sp,
                                                     float* __restrict__ adst_sp,
                                                     float* __restrict__ asrc_gs,
                                                     float* __restrict__ adst_gs,
                                                     const int* __restrict__ ei_sp,
                                                     const int* __restrict__ ei_gs,
                                                     const int* __restrict__ rs_sp,
                                                     const int* __restrict__ rs_gs,
                                                     const int* __restrict__ ord_sp,
                                                     const int* __restrict__ ord_gs,
                                                     int* __restrict__ csr_sp,
                                                     int* __restrict__ csr_gs,
                                                     int nScat, int E, int N) {
  if ((int)blockIdx.x < nScat) {
    const int m = blockIdx.x * 256 + threadIdx.x;
    if (m < E) {
      csr_sp[rs_sp[ei_sp[E + m]] + ord_sp[m]] = ei_sp[m];
      csr_gs[rs_gs[ei_gs[E + m]] + ord_gs[m]] = ei_gs[m];
    }
    return;
  }
  const int wave = (int)(((blockIdx.x - nScat) * (size_t)256 + threadIdx.x) >> 6);
  const int lane = threadIdx.x & 63;
  if (wave >= N) return;
  const ushort4 h1 = hsp[(size_t)wave * 64 + lane];
  const ushort4 h2 = hgs[(size_t)wave * 64 + lane];
  const float4 s1 = ((const float4*)av_sp_s)[lane];
  const float4 d1 = ((const float4*)av_sp_d)[lane];
  const float4 s2 = ((const float4*)av_gs_s)[lane];
  const float4 d2 = ((const float4*)av_gs_d)[lane];
  const float a0 = bf2f(h1.x), a1 = bf2f(h1.y), a2 = bf2f(h1.z), a3 = bf2f(h1.w);
  const float b0 = bf2f(h2.x), b1 = bf2f(h2.y), b2 = bf2f(h2.z), b3 = bf2f(h2.w);
  float p0 = a0 * s1.x + a1 * s1.y + a2 * s1.z + a3 * s1.w;
  float p1 = a0 * d1.x + a1 * d1.y + a2 * d1.z + a3 * d1.w;
  float p2 = b0 * s2.x + b1 * s2.y + b2 * s2.z + b3 * s2.w;
  float p3 = b0 * d2.x + b1 * d2.y + b2 * d2.z + b3 * d2.w;
#pragma unroll
  for (int off = 32; off; off >>= 1) {
    p0 += __shfl_down(p0, off);
    p1 += __shfl_down(p1, off);
    p2 += __shfl_down(p2, off);
    p3 += __shfl_down(p3, off);
  }
  if (lane == 0) {
    asrc_sp[wave] = p0; adst_sp[wave] = p1;
    asrc_gs[wave] = p2; adst_gs[wave] = p3;
  }
}

// ---------------- fusion GEMM (256->64) + in-wave alpha epilogue ----------------
__global__ __launch_bounds__(256) void gemm_fu_alpha(const unsigned short* __restrict__ A,
                                                     const unsigned short* __restrict__ Bt,
                                                     const float* __restrict__ avs,
                                                     const float* __restrict__ avd,
                                                     unsigned short* __restrict__ C,
                                                     float* __restrict__ asrc,
                                                     float* __restrict__ adst,
                                                     int M) {
  constexpr int K = 256, Nc = 64;
  __shared__ unsigned short sA[128 * 64];
  __shared__ unsigned short sB[64 * 64];
  const int tid = threadIdx.x;
  const int w = tid >> 6, l = tid & 63;
  const int bm = blockIdx.x * 128;
  const int crow = l >> 3;
  const int cbyte = (l & 7) * 16;

  f32x4 acc[2][4] = {};
  for (int k0 = 0; k0 < K; k0 += 64) {
    __syncthreads();
#pragma unroll
    for (int c = 0; c < 4; ++c) {
      const int ch = w * 4 + c;
      int row = bm + ch * 8 + crow;
      row = row < M ? row : M - 1;
      const char* g = (const char*)A + (size_t)row * K * 2 + (size_t)k0 * 2 + cbyte;
      GLOAD16(g, ((char*)sA) + ch * 1024);
    }
#pragma unroll
    for (int c = 0; c < 2; ++c) {
      const int ch = w * 2 + c;
      const int row = ch * 8 + crow;
      const char* g = (const char*)Bt + (size_t)row * K * 2 + (size_t)k0 * 2 + cbyte;
      GLOAD16(g, ((char*)sB) + ch * 1024);
    }
    __syncthreads();
#pragma unroll
    for (int ks = 0; ks < 2; ++ks) {
      bf16x8 af[2], bfr[4];
#pragma unroll
      for (int m = 0; m < 2; ++m) {
        const int r = w * 32 + m * 16 + (l & 15);
        af[m] = *(const bf16x8*)&sA[r * 64 + ks * 32 + (l >> 4) * 8];
      }
#pragma unroll
      for (int n = 0; n < 4; ++n) {
        const int r = n * 16 + (l & 15);
        bfr[n] = *(const bf16x8*)&sB[r * 64 + ks * 32 + (l >> 4) * 8];
      }
#pragma unroll
      for (int m = 0; m < 2; ++m)
#pragma unroll
        for (int n = 0; n < 4; ++n)
          acc[m][n] = __builtin_amdgcn_mfma_f32_16x16x32_bf16(af[m], bfr[n], acc[m][n], 0, 0, 0);
    }
  }
  float as_v[4], ad_v[4];
#pragma unroll
  for (int n = 0; n < 4; ++n) {
    as_v[n] = avs[n * 16 + (l & 15)];
    ad_v[n] = avd[n * 16 + (l & 15)];
  }
#pragma unroll
  for (int m = 0; m < 2; ++m) {
#pragma unroll
    for (int r = 0; r < 4; ++r) {
      const int row = bm + w * 32 + m * 16 + (l >> 4) * 4 + r;
      if (row < M) {
#pragma unroll
        for (int n = 0; n < 4; ++n)
          C[(size_t)row * Nc + n * 16 + (l & 15)] = f2bf(acc[m][n][r]);
      }
      float ps = acc[m][0][r] * as_v[0] + acc[m][1][r] * as_v[1] +
                 acc[m][2][r] * as_v[2] + acc[m][3][r] * as_v[3];
      float pd = acc[m][0][r] * ad_v[0] + acc[m][1][r] * ad_v[1] +
                 acc[m][2][r] * ad_v[2] + acc[m][3][r] * ad_v[3];
#pragma unroll
      for (int off = 1; off < 16; off <<= 1) {
        ps += __shfl_xor(ps, off);
        pd += __shfl_xor(pd, off);
      }
      if ((l & 15) == 0 && row < M) {
        asrc[row] = ps;
        adst[row] = pd;
      }
    }
  }
}

// ---------------- merged dual-graph aggregation + blend, H=256 ----------------
__global__ __launch_bounds__(256) void agg2_blend(const int* __restrict__ rs_sp,
                                                  const int* __restrict__ csr_sp,
                                                  const int* __restrict__ rs_gs,
                                                  const int* __restrict__ csr_gs,
                                                  const float* __restrict__ asrc_sp,
                                                  const float* __restrict__ adst_sp,
                                                  const float* __restrict__ asrc_gs,
                                                  const float* __restrict__ adst_gs,
                                                  const uint2* __restrict__ hsp4,
                                                  const uint2* __restrict__ hgs4,
                                                  const float* __restrict__ b_sp,
                                                  const float* __restrict__ b_gs,
                                                  ushort4* __restrict__ out16, int N) {
  const int d = (int)((blockIdx.x * (size_t)blockDim.x + threadIdx.x) >> 6);
  const int lane = threadIdx.x & 63;
  if (d >= N) return;

  float v_sp[4], v_gs[4];
#pragma unroll
  for (int g = 0; g < 2; ++g) {
    const int* __restrict__ rs   = g ? rs_gs : rs_sp;
    const int* __restrict__ csr  = g ? csr_gs : csr_sp;
    const float* __restrict__ as = g ? asrc_gs : asrc_sp;
    const float* __restrict__ adp = g ? adst_gs : adst_sp;
    const uint2* __restrict__ h4 = g ? hgs4 : hsp4;
    const float* __restrict__ bias = g ? b_gs : b_sp;
    float* __restrict__ vout = g ? v_gs : v_sp;

    const float ad = adp[d];
    float e = as[d] + ad;
    e = e > 0.f ? e : NEG_SLOPE * e;
    const float wself = expf(e);
    float denl = (lane == 0) ? wself : 0.f;
    const uint2 hv = h4[(size_t)d * 64 + lane];
    f32x2 axy = unpk(hv.x) * wself;
    f32x2 azw = unpk(hv.y) * wself;

    const int base = rs[d], mend = rs[d + 1];
    for (int c = base; c < mend; c += 64) {
      const int m = c + lane;
      int s = 0;
      float w = 0.f;
      if (m < mend) {
        s = csr[m];
        float e2 = as[s] + ad;
        e2 = e2 > 0.f ? e2 : NEG_SLOPE * e2;
        w = expf(e2);
      }
      denl += w;
      const int cnt = min(64, mend - c);
      int j = 0;
      for (; j + 3 < cnt; j += 4) {
        const int s0 = rl_i(s, j), s1 = rl_i(s, j + 1), s2 = rl_i(s, j + 2), s3 = rl_i(s, j + 3);
        const float w0 = rl_f(w, j), w1 = rl_f(w, j + 1), w2 = rl_f(w, j + 2), w3 = rl_f(w, j + 3);
        const uint2 a0 = h4[(size_t)s0 * 64 + lane];
        const uint2 a1 = h4[(size_t)s1 * 64 + lane];
        const uint2 a2 = h4[(size_t)s2 * 64 + lane];
        const uint2 a3 = h4[(size_t)s3 * 64 + lane];
        axy += unpk(a0.x) * w0;  azw += unpk(a0.y) * w0;
        axy += unpk(a1.x) * w1;  azw += unpk(a1.y) * w1;
        axy += unpk(a2.x) * w2;  azw += unpk(a2.y) * w2;
        axy += unpk(a3.x) * w3;  azw += unpk(a3.y) * w3;
      }
      for (; j < cnt; ++j) {
        const int sj = rl_i(s, j);
        const float wj = rl_f(w, j);
        const uint2 aj = h4[(size_t)sj * 64 + lane];
        axy += unpk(aj.x) * wj;
        azw += unpk(aj.y) * wj;
      }
    }
#pragma unroll
    for (int off = 32; off; off >>= 1) denl += __shfl_xor(denl, off);
    const float inv = 1.f / denl;
    const float4 b4 = ((const float4*)bias)[lane];
    vout[0] = axy.x * inv + b4.x;
    vout[1] = axy.y * inv + b4.y;
    vout[2] = azw.x * inv + b4.z;
    vout[3] = azw.y * inv + b4.w;
#pragma unroll
    for (int j2 = 0; j2 < 4; ++j2)
      vout[j2] = vout[j2] > 0.f ? vout[j2] : (expf(vout[j2]) - 1.f);
  }

  ushort4 pk;
  pk.x = f2bf(0.5f * v_gs[0] + 0.5f * v_sp[0]);
  pk.y = f2bf(0.5f * v_gs[1] + 0.5f * v_sp[1]);
  pk.z = f2bf(0.5f * v_gs[2] + 0.5f * v_sp[2]);
  pk.w = f2bf(0.5f * v_gs[3] + 0.5f * v_sp[3]);
  out16[(size_t)d * 64 + lane] = pk;
}

// ---------------- fused CSR aggregation, H=64, bf16 h -> fp32 d_out ----------------
__global__ __launch_bounds__(256) void agg_csr64(const int* __restrict__ rs,
                                                 const int* __restrict__ csr,
                                                 const float* __restrict__ asrc,
                                                 const float* __restrict__ adst,
                                                 const unsigned short* __restrict__ h,
                                                 const float* __restrict__ bias,
                                                 float* __restrict__ outb, int N) {
  const int d = (int)((blockIdx.x * (size_t)blockDim.x + threadIdx.x) >> 6);
  const int lane = threadIdx.x & 63;
  if (d >= N) return;
  const float ad = adst[d];

  float e = asrc[d] + ad;
  e = e > 0.f ? e : NEG_SLOPE * e;
  const float wself = expf(e);
  float denl = (lane == 0) ? wself : 0.f;
  f32x2 acc2;
  acc2.x = wself * bf2f(h[(size_t)d * 64 + lane]);
  acc2.y = 0.f;

  const int base = rs[d], mend = rs[d + 1];
  for (int c = base; c < mend; c += 64) {
    const int m = c + lane;
    int s = 0;
    float w = 0.f;
    if (m < mend) {
      s = csr[m];
      float e2 = asrc[s] + ad;
      e2 = e2 > 0.f ? e2 : NEG_SLOPE * e2;
      w = expf(e2);
    }
    denl += w;
    const int cnt = min(64, mend - c);
    int j = 0;
    for (; j + 3 < cnt; j += 4) {
      const int s0 = rl_i(s, j), s1 = rl_i(s, j + 1), s2 = rl_i(s, j + 2), s3 = rl_i(s, j + 3);
      const float w0 = rl_f(w, j), w1 = rl_f(w, j + 1), w2 = rl_f(w, j + 2), w3 = rl_f(w, j + 3);
      f32x2 h01, h23, w01, w23;
      h01.x = bf2f(h[(size_t)s0 * 64 + lane]);
      h01.y = bf2f(h[(size_t)s1 * 64 + lane]);
      h23.x = bf2f(h[(size_t)s2 * 64 + lane]);
      h23.y = bf2f(h[(size_t)s3 * 64 + lane]);
      w01.x = w0; w01.y = w1;
      w23.x = w2; w23.y = w3;
      acc2 += h01 * w01;
      acc2 += h23 * w23;
    }
    for (; j < cnt; ++j) {
      const int sj = rl_i(s, j);
      const float wj = rl_f(w, j);
      acc2.x += wj * bf2f(h[(size_t)sj * 64 + lane]);
    }
  }
  float acc = acc2.x + acc2.y;
#pragma unroll
  for (int off = 32; off; off >>= 1) denl += __shfl_xor(denl, off);
  outb[(size_t)d * 64 + lane] = acc / denl + bias[lane];
}

extern "C" void kernel_launch(void* const* d_in, const int* in_sizes, int n_in,
                              void* d_out, int out_size, void* d_ws, size_t ws_size,
                              hipStream_t stream) {
  const float* x        = (const float*)d_in[0];
  const int*   ei_sp    = (const int*)d_in[1];
  const int*   ei_gs    = (const int*)d_in[2];
  const float* W_sp     = (const float*)d_in[3];
  const float* a_src_sp = (const float*)d_in[4];
  const float* a_dst_sp = (const float*)d_in[5];
  const float* b_sp     = (const float*)d_in[6];
  const float* W_gs     = (const float*)d_in[7];
  const float* a_src_gs = (const float*)d_in[8];
  const float* a_dst_gs = (const float*)d_in[9];
  const float* b_gs     = (const float*)d_in[10];
  const float* W_fu     = (const float*)d_in[11];
  const float* a_src_fu = (const float*)d_in[12];
  const float* a_dst_fu = (const float*)d_in[13];
  const float* b_fu     = (const float*)d_in[14];
  float* out = (float*)d_out;

  const int N = in_sizes[0] / 512;
  const int E = in_sizes[1] / 2;
  const int nb = (N + 255) / 256;

  // ---- workspace layout ----
  unsigned short* wt_sp = (unsigned short*)d_ws;       // 256*512
  unsigned short* wt_gs = wt_sp + 256 * 512;           // 256*512
  unsigned short* wt_fu = wt_gs + 256 * 512;           // 64*256
  unsigned short* hb_sp = wt_fu + 64 * 256;            // N*256 bf16
  unsigned short* hb_gs = hb_sp + (size_t)N * 256;     // N*256 bf16
  unsigned short* hfb   = hb_gs + (size_t)N * 256;     // N*256 bf16 h_fused
  unsigned short* hfu   = hfb + (size_t)N * 256;       // N*64 bf16
  float* asrc_sp = (float*)(hfu + (size_t)N * 64);     // N
  float* adst_sp = asrc_sp + N;                        // N
  float* asrc_gs = adst_sp + N;                        // N
  float* adst_gs = asrc_gs + N;                        // N
  int* rs_sp  = (int*)(adst_gs + N);                   // N+1
  int* rs_gs  = rs_sp + (N + 1);                       // N+1
  int* csr_sp = rs_gs + (N + 1);                       // E
  int* csr_gs = csr_sp + E;                            // E
  int* deg_sp = csr_gs + E;                            // N
  int* deg_gs = deg_sp + N;                            // N
  int* parts2 = deg_gs + N;                            // 2*512
  int* ord_sp = parts2 + 1024;                         // E
  int* ord_gs = ord_sp + E;                            // E

  const int BLK = 256;
  const int nodeWaveGrid = (N + 3) / 4;
  const int nHist = (E + 511) / 512;
  const int nGemm = (N + 63) / 64;
  const int nScat = (E + 255) / 256;

  // ---- weights first (gemm2_hist's gemm blocks read them) ----
  wt_bf16_all<<<(278528 + 255) / 256, BLK, 0, stream>>>(W_sp, W_gs, W_fu,
                                                        wt_sp, wt_gs, wt_fu);
  hipMemsetAsync(deg_sp, 0, (size_t)2 * N * 4, stream);

  // ---- hybrid 1: edge histogram + layer-1 GEMMs (front-loaded hist) ----
  gemm2_hist<<<nHist + nGemm, 512, 0, stream>>>(x, wt_sp, wt_gs, hb_sp, hb_gs,
                                                ei_sp + E, ei_gs + E,
                                                deg_sp, deg_gs, ord_sp, ord_gs,
                                                nHist, E, N);

  // ---- scans ----
  scan1_2<<<dim3(nb, 2), BLK, 0, stream>>>(deg_sp, deg_gs, rs_sp, rs_gs, parts2, N);
  scan2_2<<<2, 512, 0, stream>>>(parts2, nb);
  scan3_2<<<dim3(nb, 2), BLK, 0, stream>>>(rs_sp, rs_gs, parts2, N, E);

  // ---- hybrid 2: CSR scatter + dual alpha ----
  alpha_scatter<<<nScat + nodeWaveGrid, BLK, 0, stream>>>(
      (const ushort4*)hb_sp, (const ushort4*)hb_gs,
      a_src_sp, a_dst_sp, a_src_gs, a_dst_gs,
      asrc_sp, adst_sp, asrc_gs, adst_gs,
      ei_sp, ei_gs, rs_sp, rs_gs, ord_sp, ord_gs,
      csr_sp, csr_gs, nScat, E, N);

  // ---- merged dual-graph aggregation + blend -> h_fused bf16 ----
  agg2_blend<<<nodeWaveGrid, BLK, 0, stream>>>(rs_sp, csr_sp, rs_gs, csr_gs,
                                               asrc_sp, adst_sp, asrc_gs, adst_gs,
                                               (const uint2*)hb_sp,
                                               (const uint2*)hb_gs,
                                               b_sp, b_gs, (ushort4*)hfb, N);

  // ---- fusion conv (256->64, spatial graph) + in-wave alpha epilogue ----
  gemm_fu_alpha<<<(N + 127) / 128, BLK, 0, stream>>>(hfb, wt_fu, a_src_fu, a_dst_fu,
                                                     hfu, asrc_sp, adst_sp, N);
  agg_csr64<<<nodeWaveGrid, BLK, 0, stream>>>(rs_sp, csr_sp, asrc_sp, adst_sp,
                                              hfu, b_fu, out, N);
}